// Round 27
// baseline (129.597 us; speedup 1.0000x reference)
//
#include <hip/hip_runtime.h>

#define DEVI __device__ __forceinline__

typedef __bf16 bf16x8 __attribute__((ext_vector_type(8)));
typedef float  f32x4  __attribute__((ext_vector_type(4)));

static DEVI unsigned short f2bf(float f) {
  unsigned u = __builtin_bit_cast(unsigned, f);
  u = u + 0x7fffu + ((u >> 16) & 1u);   // RTNE (no NaN inputs here)
  return (unsigned short)(u >> 16);
}
static DEVI unsigned short f2bf_trunc(float f) {      // truncation: 1 op; fine for P >= 0
  return (unsigned short)(__builtin_bit_cast(unsigned, f) >> 16);
}

#define EXP2F(x) __builtin_amdgcn_exp2f(x)   // v_exp_f32 (base-2 native)

typedef __attribute__((address_space(3))) void* lds_vp;
typedef const __attribute__((address_space(1))) void* glob_vp;
#define GL2LDS16(g, l) __builtin_amdgcn_global_load_lds((glob_vp)(g), (lds_vp)(l), 16, 0, 0)

// ---------------- f32 -> bf16 convert: all three inputs in ONE launch ----------------
__global__ void __launch_bounds__(256) conv3_bf16(
    const float* __restrict__ x,  const float* __restrict__ wa, const float* __restrict__ wp,
    unsigned short* __restrict__ xb, unsigned short* __restrict__ wab, unsigned short* __restrict__ wpb) {
  const int i = (int)blockIdx.x * 256 + (int)threadIdx.x;     // in float4 units
  const float* in; unsigned short* out; int off;
  if (i < 1048576)               { in = x;  out = xb;  off = i; }
  else if (i < 1048576 + 786432) { in = wa; out = wab; off = i - 1048576; }
  else                           { in = wp; out = wpb; off = i - (1048576 + 786432); }
  float4 v = reinterpret_cast<const float4*>(in)[off];
  ushort4 o;
  o.x = f2bf(v.x); o.y = f2bf(v.y); o.z = f2bf(v.z); o.w = f2bf(v.w);
  reinterpret_cast<ushort4*>(out)[off] = o;
}

// ---------------- GEMM C[r][c] = sum_k A[r][k]*Bm[c][k]  (both K-contiguous) ----------------
// Catalog T3-minimum single-barrier pipeline: dbuf BK=64; per tile {stage next -> ds_read cur
// -> MFMA -> __syncthreads (vmcnt0+lgkm0 drain)}. 16 barriers/block (was 32). T2 swizzle.
#define GSTAGE(t_, bufi_) do {                                                    \
    const int kk_ = (t_)*64;                                                      \
    _Pragma("unroll")                                                             \
    for (int jq = 0; jq < 4; jq++) {                                              \
      const int row_ = w*32 + jq*8 + (l >> 3);                                    \
      GL2LDS16(A  + (size_t)(r0 + row_)*K + kk_ + scol, &sA[bufi_][(w*32 + jq*8)*64]); \
      GL2LDS16(Bm + (size_t)(c0 + row_)*K + kk_ + scol, &sB[bufi_][(w*32 + jq*8)*64]); \
    } } while (0)

template<int EPI>
__global__ void __launch_bounds__(256) gemm_bt(
    const unsigned short* __restrict__ A,    // [M][1024] bf16
    const unsigned short* __restrict__ Bm,   // [N][1024] bf16
    const float* __restrict__ bias,          // [N]
    const float* __restrict__ bV,            // [16*64] (EPI 0)
    unsigned short* __restrict__ outQ,       // [B,H,T,D]
    unsigned short* __restrict__ outK,       // [B,H,T,D]
    unsigned short* __restrict__ outVT,      // [B,H,D,T]
    float* __restrict__ outF)                // [M][1024] (EPI 1)
{
  constexpr int K = 1024;
  constexpr int NSTEP = 16;                  // K / 64
  __shared__ unsigned short sA[2][128*64];
  __shared__ unsigned short sB[2][128*64];
  const int tid = (int)threadIdx.x;
  const int w = tid >> 6;
  const int l = tid & 63;
  const int l15 = l & 15, lg = l >> 4;
  const int r0 = (int)blockIdx.y * 128;
  const int c0 = (int)blockIdx.x * 128;
  const int wr = (w >> 1) * 64, wc = (w & 1) * 64;
  const int scol = ((l & 7) ^ (l >> 3)) * 8;   // pre-swizzled source colblock (rule #21)
  const int rdsw = (l & 7) * 8;                // read-side XOR (row&7)*8

  f32x4 acc[4][4];
#pragma unroll
  for (int i = 0; i < 4; i++)
#pragma unroll
    for (int j = 0; j < 4; j++) acc[i][j] = (f32x4){0.f, 0.f, 0.f, 0.f};

  GSTAGE(0, 0);
  __syncthreads();                             // tile 0 landed (vmcnt0 drain + barrier)
  for (int t = 0; t < NSTEP; t++) {
    const int bufi = t & 1;
    if (t + 1 < NSTEP) GSTAGE(t + 1, bufi ^ 1);  // issue next tile FIRST; flies under read+MFMA
    bf16x8 av[2][4], bv[2][4];
#pragma unroll
    for (int ks = 0; ks < 2; ks++) {
#pragma unroll
      for (int mi = 0; mi < 4; mi++)
        av[ks][mi] = *(const bf16x8*)&sA[bufi][(wr + mi*16 + l15)*64 + ((ks*32 + lg*8) ^ rdsw)];
#pragma unroll
      for (int ni = 0; ni < 4; ni++)
        bv[ks][ni] = *(const bf16x8*)&sB[bufi][(wc + ni*16 + l15)*64 + ((ks*32 + lg*8) ^ rdsw)];
    }
    __builtin_amdgcn_s_setprio(1);
#pragma unroll
    for (int ks = 0; ks < 2; ks++)
#pragma unroll
      for (int mi = 0; mi < 4; mi++)
#pragma unroll
        for (int ni = 0; ni < 4; ni++)
          acc[mi][ni] = __builtin_amdgcn_mfma_f32_16x16x32_bf16(av[ks][mi], bv[ks][ni], acc[mi][ni], 0, 0, 0);
    __builtin_amdgcn_s_setprio(0);
    __syncthreads();                           // drain: my stage landed, my reads done; buf swap safe
  }

#pragma unroll
  for (int mi = 0; mi < 4; mi++) {
    const int rbase = r0 + wr + mi*16 + lg*4;
#pragma unroll
    for (int ni = 0; ni < 4; ni++) {
      const int c = c0 + wc + ni*16 + l15;
      const float bsv = bias[c];
      if constexpr (EPI == 0) {
        const int which = c >> 10;        // 0=q 1=k 2=v (tile never crosses sections)
        const int cc = c & 1023;
        const int h = cc >> 6;
        const int d = cc & 63;
        const float bvv = (which == 2) ? bV[h*64 + d] : 0.f;
#pragma unroll
        for (int i = 0; i < 4; i++) {
          const int rr = rbase + i;
          const int b = rr >> 11;
          const int t = rr & 2047;
          const int bh = b*16 + h;
          const float v = acc[mi][ni][i] + bsv;
          // 0.125 (1/sqrt(D)) * log2(e): softmax runs in base-2
          if (which == 0)      outQ[((size_t)bh*2048 + t)*64 + d] = f2bf(v * 0.1803368801f);
          else if (which == 1) outK[((size_t)bh*2048 + t)*64 + d] = f2bf(v);
          else                 outVT[((size_t)bh*64 + d)*2048 + t] = f2bf(v + bvv);
        }
      } else {
#pragma unroll
        for (int i = 0; i < 4; i++)
          outF[(size_t)(rbase + i)*1024 + c] = acc[mi][ni][i] + bsv;
      }
    }
  }
}

// ---------------- causal flash attention (R15-measured version, unchanged) ----------------
// grid: (bh=32, qtile=32 reversed), 256 thr (4 waves x 16 q-rows).
// Double-buffered K/V staging with counted vmcnt (T4); XOR-swizzled LDS (T2); setprio (T5).
// FIXED-REFERENCE softmax (scores O(+-10) in base-2; exp2 direct, sum-normalize at end).
#define ASTAGE(kt_, bufi_) do {                                                   \
    _Pragma("unroll")                                                             \
    for (int jq = 0; jq < 2; jq++) {                                              \
      const int chunk_ = w*2 + jq;                                                \
      GL2LDS16(Kh + (size_t)((kt_)*64 + chunk_*8 + (l >> 3))*64 + srcsw, &sK[bufi_][chunk_*512]); \
      GL2LDS16(Vh + (size_t)(chunk_*8 + (l >> 3))*2048 + (kt_)*64 + srcsw, &sV[bufi_][chunk_*512]); \
    } } while (0)

__global__ void __launch_bounds__(256) attn_fwd(
    const unsigned short* __restrict__ Q,   // [BH][2048][64]
    const unsigned short* __restrict__ Kc,  // [BH][2048][64]
    const unsigned short* __restrict__ VT,  // [BH][64][2048]
    unsigned short* __restrict__ att)       // [4096][1024] bf16
{
  __shared__ unsigned short sK[2][64*64];    // [key][d], swizzled
  __shared__ unsigned short sV[2][64*64];    // [d][key], swizzled
  __shared__ unsigned short sP[4][16*64];    // per-wave, XOR-swizzled

  const int tid = (int)threadIdx.x;
  const int w = tid >> 6, l = tid & 63;
  const int l15 = l & 15, lg = l >> 4;
  const int bh = (int)blockIdx.x;
  const int qt = (int)gridDim.y - 1 - (int)blockIdx.y;  // heavy tiles first
  const int qw = qt * 64 + w * 16;

  const unsigned short* Qh = Q  + (size_t)bh * (2048*64);
  const unsigned short* Kh = Kc + (size_t)bh * (2048*64);
  const unsigned short* Vh = VT + (size_t)bh * (2048*64);

  bf16x8 qf[2];
#pragma unroll
  for (int ks = 0; ks < 2; ks++)
    qf[ks] = *(const bf16x8*)&Qh[(size_t)(qw + l15)*64 + ks*32 + lg*8];

  f32x4 o[4];
#pragma unroll
  for (int nd = 0; nd < 4; nd++) o[nd] = (f32x4){0.f, 0.f, 0.f, 0.f};
  float lpart[4];
#pragma unroll
  for (int i = 0; i < 4; i++) lpart[i] = 0.f;

  const int srcsw = ((l & 7) ^ (l >> 3)) * 8;   // pre-swizzled source col (shorts)
  const int rdsw  = (l15 & 7) * 8;              // read-side XOR (shorts)

  ASTAGE(0, 0);
  if (qt >= 1) ASTAGE(1, 1);
  for (int kt = 0; kt <= qt; kt++) {
    if (kt < qt) asm volatile("s_waitcnt vmcnt(4)" ::: "memory");  // tile kt landed, kt+1 in flight
    else         asm volatile("s_waitcnt vmcnt(0)" ::: "memory");
    __builtin_amdgcn_s_barrier();
    const int bufi = kt & 1;
    {
      f32x4 s[4];
#pragma unroll
      for (int ni = 0; ni < 4; ni++) s[ni] = (f32x4){0.f, 0.f, 0.f, 0.f};
#pragma unroll
      for (int ks = 0; ks < 2; ks++) {
        bf16x8 kb[4];
#pragma unroll
        for (int ni = 0; ni < 4; ni++)
          kb[ni] = *(const bf16x8*)&sK[bufi][(ni*16 + l15)*64 + ((ks*32 + lg*8) ^ rdsw)];
        __builtin_amdgcn_s_setprio(1);
#pragma unroll
        for (int ni = 0; ni < 4; ni++)
          s[ni] = __builtin_amdgcn_mfma_f32_16x16x32_bf16(qf[ks], kb[ni], s[ni], 0, 0, 0);
        __builtin_amdgcn_s_setprio(0);
      }
      if (kt == qt) {                           // diagonal tile: mask key > q
#pragma unroll
        for (int i = 0; i < 4; i++) {
          const int qq = qw + lg*4 + i;
#pragma unroll
          for (int ni = 0; ni < 4; ni++) {
            const int key = kt*64 + ni*16 + l15;
            if (key > qq) s[ni][i] = -1e30f;
          }
        }
      }
      unsigned short* pw = &sP[w][0];
#pragma unroll
      for (int i = 0; i < 4; i++) {
        float ps = 0.f;
        const int row = lg*4 + i;
        const int psw = (row & 7) << 3;         // sP write-side XOR
#pragma unroll
        for (int ni = 0; ni < 4; ni++) {
          const float p = EXP2F(s[ni][i]);      // fixed reference: no max subtraction
          ps += p;
          pw[row*64 + ((ni*16 + l15) ^ psw)] = f2bf_trunc(p);
        }
        lpart[i] += ps;
      }
#pragma unroll
      for (int ks = 0; ks < 2; ks++) {
        bf16x8 pf, vb[4];
        pf = *(const bf16x8*)&pw[l15*64 + ((ks*32 + lg*8) ^ rdsw)];   // sP read-side XOR (row=l15)
#pragma unroll
        for (int nd = 0; nd < 4; nd++)
          vb[nd] = *(const bf16x8*)&sV[bufi][(nd*16 + l15)*64 + ((ks*32 + lg*8) ^ rdsw)];
        __builtin_amdgcn_s_setprio(1);
#pragma unroll
        for (int nd = 0; nd < 4; nd++)
          o[nd] = __builtin_amdgcn_mfma_f32_16x16x32_bf16(pf, vb[nd], o[nd], 0, 0, 0);
        __builtin_amdgcn_s_setprio(0);
      }
    }
    asm volatile("s_waitcnt lgkmcnt(0)" ::: "memory");   // LDS reads done before overwrite
    __builtin_amdgcn_s_barrier();
    if (kt + 2 <= qt) ASTAGE(kt + 2, bufi);              // loads fly during next step
  }

  const int b = bh >> 4, h = bh & 15;
#pragma unroll
  for (int i = 0; i < 4; i++) {
    float lp = lpart[i];
    lp += __shfl_xor(lp, 1);
    lp += __shfl_xor(lp, 2);
    lp += __shfl_xor(lp, 4);
    lp += __shfl_xor(lp, 8);
    const float rinv = 1.0f / lp;
    const int qq = qw + lg*4 + i;
#pragma unroll
    for (int nd = 0; nd < 4; nd++) {
      const int d = nd*16 + l15;
      att[((size_t)(b*2048 + qq))*1024 + h*64 + d] = f2bf(o[nd][i] * rinv);
    }
  }
}

// ---------------- launch ----------------
extern "C" void kernel_launch(void* const* d_in, const int* in_sizes, int n_in,
                              void* d_out, int out_size, void* d_ws, size_t ws_size,
                              hipStream_t stream) {
  const float* x      = (const float*)d_in[0];
  const float* W_attn = (const float*)d_in[1];
  const float* b_attn = (const float*)d_in[2];
  const float* W_proj = (const float*)d_in[3];
  const float* b_proj = (const float*)d_in[4];
  const float* bV     = (const float*)d_in[5];
  float* out = (float*)d_out;
  char* ws = (char*)d_ws;

  unsigned short* xb   = (unsigned short*)(ws);                    //  8 MB [4096][1024]
  unsigned short* wab  = (unsigned short*)(ws + (8u  << 20));      //  6 MB [3072][1024]
  unsigned short* wpb  = (unsigned short*)(ws + (14u << 20));      //  2 MB [1024][1024]
  unsigned short* qb   = (unsigned short*)(ws + (16u << 20));      //  8 MB [BH][T][D] (pre-scaled)
  unsigned short* kb   = (unsigned short*)(ws + (24u << 20));      //  8 MB [BH][T][D]
  unsigned short* vtb  = (unsigned short*)(ws + (32u << 20));      //  8 MB [BH][D][T]
  unsigned short* attb = (unsigned short*)(ws + (40u << 20));      //  8 MB [4096][1024]

  conv3_bf16<<<8192, 256, 0, stream>>>(x, W_attn, W_proj, xb, wab, wpb);

  gemm_bt<0><<<dim3(24, 32), 256, 0, stream>>>(xb, wab, b_attn, bV, qb, kb, vtb, nullptr);
  attn_fwd<<<dim3(32, 32), 256, 0, stream>>>(qb, kb, vtb, attb);
  gemm_bt<1><<<dim3(8, 32), 256, 0, stream>>>(attb, wpb, b_proj, nullptr, nullptr, nullptr, nullptr, out);
}

// Round 28
// 117.886 us; speedup vs baseline: 1.0993x; 1.0993x over previous
//
#include <hip/hip_runtime.h>

#define DEVI __device__ __forceinline__

typedef __bf16 bf16x8 __attribute__((ext_vector_type(8)));
typedef float  f32x4  __attribute__((ext_vector_type(4)));

static DEVI unsigned short f2bf(float f) {
  unsigned u = __builtin_bit_cast(unsigned, f);
  u = u + 0x7fffu + ((u >> 16) & 1u);   // RTNE (no NaN inputs here)
  return (unsigned short)(u >> 16);
}
static DEVI unsigned short f2bf_trunc(float f) {      // truncation: 1 op; fine for P >= 0
  return (unsigned short)(__builtin_bit_cast(unsigned, f) >> 16);
}

#define EXP2F(x) __builtin_amdgcn_exp2f(x)   // v_exp_f32 (base-2 native)

typedef __attribute__((address_space(3))) void* lds_vp;
typedef const __attribute__((address_space(1))) void* glob_vp;
#define GL2LDS16(g, l) __builtin_amdgcn_global_load_lds((glob_vp)(g), (lds_vp)(l), 16, 0, 0)

// ---------------- f32 -> bf16 convert: all three inputs in ONE launch ----------------
__global__ void __launch_bounds__(256) conv3_bf16(
    const float* __restrict__ x,  const float* __restrict__ wa, const float* __restrict__ wp,
    unsigned short* __restrict__ xb, unsigned short* __restrict__ wab, unsigned short* __restrict__ wpb) {
  const int i = (int)blockIdx.x * 256 + (int)threadIdx.x;     // in float4 units
  const float* in; unsigned short* out; int off;
  if (i < 1048576)               { in = x;  out = xb;  off = i; }
  else if (i < 1048576 + 786432) { in = wa; out = wab; off = i - 1048576; }
  else                           { in = wp; out = wpb; off = i - (1048576 + 786432); }
  float4 v = reinterpret_cast<const float4*>(in)[off];
  ushort4 o;
  o.x = f2bf(v.x); o.y = f2bf(v.y); o.z = f2bf(v.z); o.w = f2bf(v.w);
  reinterpret_cast<ushort4*>(out)[off] = o;
}

// ---------------- GEMM C[r][c] = sum_k A[r][k]*Bm[c][k]  (both K-contiguous) ----------------
// R15/R26-measured variant: BK=64, double-buffered LDS, counted vmcnt (T4), XOR-swizzled LDS (T2).
#define GSTAGE(t_, bufi_) do {                                                    \
    const int kk_ = (t_)*64;                                                      \
    _Pragma("unroll")                                                             \
    for (int jq = 0; jq < 4; jq++) {                                              \
      const int row_ = w*32 + jq*8 + (l >> 3);                                    \
      GL2LDS16(A  + (size_t)(r0 + row_)*K + kk_ + scol, &sA[bufi_][(w*32 + jq*8)*64]); \
      GL2LDS16(Bm + (size_t)(c0 + row_)*K + kk_ + scol, &sB[bufi_][(w*32 + jq*8)*64]); \
    } } while (0)

template<int EPI>
__global__ void __launch_bounds__(256) gemm_bt(
    const unsigned short* __restrict__ A,    // [M][1024] bf16
    const unsigned short* __restrict__ Bm,   // [N][1024] bf16
    const float* __restrict__ bias,          // [N]
    const float* __restrict__ bV,            // [16*64] (EPI 0)
    unsigned short* __restrict__ outQ,       // [B,H,T,D]
    unsigned short* __restrict__ outK,       // [B,H,T,D]
    unsigned short* __restrict__ outVT,      // [B,H,D,T]
    float* __restrict__ outF)                // [M][1024] (EPI 1)
{
  constexpr int K = 1024;
  constexpr int NSTEP = 16;                  // K / 64
  __shared__ unsigned short sA[2][128*64];
  __shared__ unsigned short sB[2][128*64];
  const int tid = (int)threadIdx.x;
  const int w = tid >> 6;
  const int l = tid & 63;
  const int l15 = l & 15, lg = l >> 4;
  const int r0 = (int)blockIdx.y * 128;
  const int c0 = (int)blockIdx.x * 128;
  const int wr = (w >> 1) * 64, wc = (w & 1) * 64;
  const int scol = ((l & 7) ^ (l >> 3)) * 8;   // pre-swizzled source colblock (rule #21)
  const int rdsw = (l & 7) * 8;                // read-side XOR (row&7)*8

  f32x4 acc[4][4];
#pragma unroll
  for (int i = 0; i < 4; i++)
#pragma unroll
    for (int j = 0; j < 4; j++) acc[i][j] = (f32x4){0.f, 0.f, 0.f, 0.f};

  GSTAGE(0, 0);
  GSTAGE(1, 1);
  for (int t = 0; t < NSTEP; t++) {
    if (t < NSTEP-1) asm volatile("s_waitcnt vmcnt(8)" ::: "memory");  // tile t landed, t+1 in flight
    else             asm volatile("s_waitcnt vmcnt(0)" ::: "memory");
    __builtin_amdgcn_s_barrier();
    const int bufi = t & 1;
    bf16x8 av[2][4], bv[2][4];
#pragma unroll
    for (int ks = 0; ks < 2; ks++) {
#pragma unroll
      for (int mi = 0; mi < 4; mi++)
        av[ks][mi] = *(const bf16x8*)&sA[bufi][(wr + mi*16 + l15)*64 + ((ks*32 + lg*8) ^ rdsw)];
#pragma unroll
      for (int ni = 0; ni < 4; ni++)
        bv[ks][ni] = *(const bf16x8*)&sB[bufi][(wc + ni*16 + l15)*64 + ((ks*32 + lg*8) ^ rdsw)];
    }
    asm volatile("s_waitcnt lgkmcnt(0)" ::: "memory");   // reads in regs before overwrite
    __builtin_amdgcn_s_barrier();
    if (t + 2 < NSTEP) GSTAGE(t + 2, bufi);              // loads fly during MFMA + next step
#pragma unroll
    for (int ks = 0; ks < 2; ks++)
#pragma unroll
      for (int mi = 0; mi < 4; mi++)
#pragma unroll
        for (int ni = 0; ni < 4; ni++)
          acc[mi][ni] = __builtin_amdgcn_mfma_f32_16x16x32_bf16(av[ks][mi], bv[ks][ni], acc[mi][ni], 0, 0, 0);
  }

#pragma unroll
  for (int mi = 0; mi < 4; mi++) {
    const int rbase = r0 + wr + mi*16 + lg*4;
#pragma unroll
    for (int ni = 0; ni < 4; ni++) {
      const int c = c0 + wc + ni*16 + l15;
      const float bsv = bias[c];
      if constexpr (EPI == 0) {
        const int which = c >> 10;        // 0=q 1=k 2=v (tile never crosses sections)
        const int cc = c & 1023;
        const int h = cc >> 6;
        const int d = cc & 63;
        const float bvv = (which == 2) ? bV[h*64 + d] : 0.f;
#pragma unroll
        for (int i = 0; i < 4; i++) {
          const int rr = rbase + i;
          const int b = rr >> 11;
          const int t = rr & 2047;
          const int bh = b*16 + h;
          const float v = acc[mi][ni][i] + bsv;
          // 0.125 (1/sqrt(D)) * log2(e): softmax runs in base-2
          if (which == 0)      outQ[((size_t)bh*2048 + t)*64 + d] = f2bf(v * 0.1803368801f);
          else if (which == 1) outK[((size_t)bh*2048 + t)*64 + d] = f2bf(v);
          else                 outVT[((size_t)bh*64 + d)*2048 + t] = f2bf(v + bvv);
        }
      } else {
#pragma unroll
        for (int i = 0; i < 4; i++)
          outF[(size_t)(rbase + i)*1024 + c] = acc[mi][ni][i] + bsv;
      }
    }
  }
}

// ---------------- causal flash attention (R15-measured version, unchanged) ----------------
// grid: (bh=32, qtile=32 reversed), 256 thr (4 waves x 16 q-rows).
// Double-buffered K/V staging with counted vmcnt (T4); XOR-swizzled LDS (T2); setprio (T5).
// FIXED-REFERENCE softmax (scores O(+-10) in base-2; exp2 direct, sum-normalize at end).
#define ASTAGE(kt_, bufi_) do {                                                   \
    _Pragma("unroll")                                                             \
    for (int jq = 0; jq < 2; jq++) {                                              \
      const int chunk_ = w*2 + jq;                                                \
      GL2LDS16(Kh + (size_t)((kt_)*64 + chunk_*8 + (l >> 3))*64 + srcsw, &sK[bufi_][chunk_*512]); \
      GL2LDS16(Vh + (size_t)(chunk_*8 + (l >> 3))*2048 + (kt_)*64 + srcsw, &sV[bufi_][chunk_*512]); \
    } } while (0)

__global__ void __launch_bounds__(256) attn_fwd(
    const unsigned short* __restrict__ Q,   // [BH][2048][64]
    const unsigned short* __restrict__ Kc,  // [BH][2048][64]
    const unsigned short* __restrict__ VT,  // [BH][64][2048]
    unsigned short* __restrict__ att)       // [4096][1024] bf16
{
  __shared__ unsigned short sK[2][64*64];    // [key][d], swizzled
  __shared__ unsigned short sV[2][64*64];    // [d][key], swizzled
  __shared__ unsigned short sP[4][16*64];    // per-wave, XOR-swizzled

  const int tid = (int)threadIdx.x;
  const int w = tid >> 6, l = tid & 63;
  const int l15 = l & 15, lg = l >> 4;
  const int bh = (int)blockIdx.x;
  const int qt = (int)gridDim.y - 1 - (int)blockIdx.y;  // heavy tiles first
  const int qw = qt * 64 + w * 16;

  const unsigned short* Qh = Q  + (size_t)bh * (2048*64);
  const unsigned short* Kh = Kc + (size_t)bh * (2048*64);
  const unsigned short* Vh = VT + (size_t)bh * (2048*64);

  bf16x8 qf[2];
#pragma unroll
  for (int ks = 0; ks < 2; ks++)
    qf[ks] = *(const bf16x8*)&Qh[(size_t)(qw + l15)*64 + ks*32 + lg*8];

  f32x4 o[4];
#pragma unroll
  for (int nd = 0; nd < 4; nd++) o[nd] = (f32x4){0.f, 0.f, 0.f, 0.f};
  float lpart[4];
#pragma unroll
  for (int i = 0; i < 4; i++) lpart[i] = 0.f;

  const int srcsw = ((l & 7) ^ (l >> 3)) * 8;   // pre-swizzled source col (shorts)
  const int rdsw  = (l15 & 7) * 8;              // read-side XOR (shorts)

  ASTAGE(0, 0);
  if (qt >= 1) ASTAGE(1, 1);
  for (int kt = 0; kt <= qt; kt++) {
    if (kt < qt) asm volatile("s_waitcnt vmcnt(4)" ::: "memory");  // tile kt landed, kt+1 in flight
    else         asm volatile("s_waitcnt vmcnt(0)" ::: "memory");
    __builtin_amdgcn_s_barrier();
    const int bufi = kt & 1;
    {
      f32x4 s[4];
#pragma unroll
      for (int ni = 0; ni < 4; ni++) s[ni] = (f32x4){0.f, 0.f, 0.f, 0.f};
#pragma unroll
      for (int ks = 0; ks < 2; ks++) {
        bf16x8 kb[4];
#pragma unroll
        for (int ni = 0; ni < 4; ni++)
          kb[ni] = *(const bf16x8*)&sK[bufi][(ni*16 + l15)*64 + ((ks*32 + lg*8) ^ rdsw)];
        __builtin_amdgcn_s_setprio(1);
#pragma unroll
        for (int ni = 0; ni < 4; ni++)
          s[ni] = __builtin_amdgcn_mfma_f32_16x16x32_bf16(qf[ks], kb[ni], s[ni], 0, 0, 0);
        __builtin_amdgcn_s_setprio(0);
      }
      if (kt == qt) {                           // diagonal tile: mask key > q
#pragma unroll
        for (int i = 0; i < 4; i++) {
          const int qq = qw + lg*4 + i;
#pragma unroll
          for (int ni = 0; ni < 4; ni++) {
            const int key = kt*64 + ni*16 + l15;
            if (key > qq) s[ni][i] = -1e30f;
          }
        }
      }
      unsigned short* pw = &sP[w][0];
#pragma unroll
      for (int i = 0; i < 4; i++) {
        float ps = 0.f;
        const int row = lg*4 + i;
        const int psw = (row & 7) << 3;         // sP write-side XOR
#pragma unroll
        for (int ni = 0; ni < 4; ni++) {
          const float p = EXP2F(s[ni][i]);      // fixed reference: no max subtraction
          ps += p;
          pw[row*64 + ((ni*16 + l15) ^ psw)] = f2bf_trunc(p);
        }
        lpart[i] += ps;
      }
#pragma unroll
      for (int ks = 0; ks < 2; ks++) {
        bf16x8 pf, vb[4];
        pf = *(const bf16x8*)&pw[l15*64 + ((ks*32 + lg*8) ^ rdsw)];   // sP read-side XOR (row=l15)
#pragma unroll
        for (int nd = 0; nd < 4; nd++)
          vb[nd] = *(const bf16x8*)&sV[bufi][(nd*16 + l15)*64 + ((ks*32 + lg*8) ^ rdsw)];
        __builtin_amdgcn_s_setprio(1);
#pragma unroll
        for (int nd = 0; nd < 4; nd++)
          o[nd] = __builtin_amdgcn_mfma_f32_16x16x32_bf16(pf, vb[nd], o[nd], 0, 0, 0);
        __builtin_amdgcn_s_setprio(0);
      }
    }
    asm volatile("s_waitcnt lgkmcnt(0)" ::: "memory");   // LDS reads done before overwrite
    __builtin_amdgcn_s_barrier();
    if (kt + 2 <= qt) ASTAGE(kt + 2, bufi);              // loads fly during next step
  }

  const int b = bh >> 4, h = bh & 15;
#pragma unroll
  for (int i = 0; i < 4; i++) {
    float lp = lpart[i];
    lp += __shfl_xor(lp, 1);
    lp += __shfl_xor(lp, 2);
    lp += __shfl_xor(lp, 4);
    lp += __shfl_xor(lp, 8);
    const float rinv = 1.0f / lp;
    const int qq = qw + lg*4 + i;
#pragma unroll
    for (int nd = 0; nd < 4; nd++) {
      const int d = nd*16 + l15;
      att[((size_t)(b*2048 + qq))*1024 + h*64 + d] = f2bf(o[nd][i] * rinv);
    }
  }
}

// ---------------- launch ----------------
extern "C" void kernel_launch(void* const* d_in, const int* in_sizes, int n_in,
                              void* d_out, int out_size, void* d_ws, size_t ws_size,
                              hipStream_t stream) {
  const float* x      = (const float*)d_in[0];
  const float* W_attn = (const float*)d_in[1];
  const float* b_attn = (const float*)d_in[2];
  const float* W_proj = (const float*)d_in[3];
  const float* b_proj = (const float*)d_in[4];
  const float* bV     = (const float*)d_in[5];
  float* out = (float*)d_out;
  char* ws = (char*)d_ws;

  unsigned short* xb   = (unsigned short*)(ws);                    //  8 MB [4096][1024]
  unsigned short* wab  = (unsigned short*)(ws + (8u  << 20));      //  6 MB [3072][1024]
  unsigned short* wpb  = (unsigned short*)(ws + (14u << 20));      //  2 MB [1024][1024]
  unsigned short* qb   = (unsigned short*)(ws + (16u << 20));      //  8 MB [BH][T][D] (pre-scaled)
  unsigned short* kb   = (unsigned short*)(ws + (24u << 20));      //  8 MB [BH][T][D]
  unsigned short* vtb  = (unsigned short*)(ws + (32u << 20));      //  8 MB [BH][D][T]
  unsigned short* attb = (unsigned short*)(ws + (40u << 20));      //  8 MB [4096][1024]

  conv3_bf16<<<8192, 256, 0, stream>>>(x, W_attn, W_proj, xb, wab, wpb);

  gemm_bt<0><<<dim3(24, 32), 256, 0, stream>>>(xb, wab, b_attn, bV, qb, kb, vtb, nullptr);
  attn_fwd<<<dim3(32, 32), 256, 0, stream>>>(qb, kb, vtb, attb);
  gemm_bt<1><<<dim3(8, 32), 256, 0, stream>>>(attb, wpb, b_proj, nullptr, nullptr, nullptr, nullptr, out);
}